// Round 4
// baseline (548.947 us; speedup 1.0000x reference)
//
#include <hip/hip_runtime.h>
#include <math.h>

#define BB 4
#define TT 4096
#define DDIM 2048
#define PP 256                 // DD_PAIRS
#define MM (BB*TT)             // 16384 rows
#define KKDIM 2048
#define CHUNK 32
#define NCHUNK (TT/CHUNK)      // 128

typedef __attribute__((ext_vector_type(8))) short short8;   // 8 bf16 (4 VGPRs)
typedef __attribute__((ext_vector_type(4))) float f32x4;    // MFMA C/D

__device__ __forceinline__ unsigned short f2bf(float f) {
    unsigned u = __float_as_uint(f);
    u += 0x7FFF + ((u >> 16) & 1);          // round-to-nearest-even
    return (unsigned short)(u >> 16);
}
__device__ __forceinline__ float bf2f(unsigned short h) {
    return __uint_as_float(((unsigned)h) << 16);
}

// ===========================================================================
// K0: fp32 -> (hi, lo) bf16 split, one float4 per thread.
// ===========================================================================
__global__ __launch_bounds__(256) void cvt_k(const float* __restrict__ src,
                                             unsigned short* __restrict__ hi,
                                             unsigned short* __restrict__ lo) {
    size_t i = ((size_t)blockIdx.x * 256 + threadIdx.x) * 4;
    float4 v = *(const float4*)(src + i);
    unsigned short h0 = f2bf(v.x), h1 = f2bf(v.y), h2 = f2bf(v.z), h3 = f2bf(v.w);
    unsigned short l0 = f2bf(v.x - bf2f(h0)), l1 = f2bf(v.y - bf2f(h1));
    unsigned short l2 = f2bf(v.z - bf2f(h2)), l3 = f2bf(v.w - bf2f(h3));
    uint2 hp = { (unsigned)h0 | ((unsigned)h1 << 16), (unsigned)h2 | ((unsigned)h3 << 16) };
    uint2 lp = { (unsigned)l0 | ((unsigned)l1 << 16), (unsigned)l2 | ((unsigned)l3 << 16) };
    *(uint2*)(hi + i) = hp;
    *(uint2*)(lo + i) = lp;
}

// ===========================================================================
// K1 (tier 1): pure-bf16 MFMA GEMM from precomputed hi/lo, fused chunk sums.
// Block 64M x 128N, 128 threads = 2 waves; wave wn: full 64 M x 64 N slice.
// mt=nt=4 of 16x16x32 (layout verified in round 3), 3 products (hh, hl, lh).
// LDS row stride 40 shorts (80 B): fragment reads are 2-way-conflict max.
// ===========================================================================
#define LS 40

__global__ __launch_bounds__(128) void gemm_bf16_k(
        const unsigned short* __restrict__ xhi, const unsigned short* __restrict__ xlo,
        const unsigned short* __restrict__ whi, const unsigned short* __restrict__ wlo,
        const float* __restrict__ bias,
        float* __restrict__ delta, float* __restrict__ csum) {
    __shared__ unsigned short Ah[64 * LS], Al[64 * LS];
    __shared__ unsigned short Bh[128 * LS], Bl[128 * LS];
    const int n0   = blockIdx.x * 128;
    const int m0   = blockIdx.y * 64;
    const int tid  = threadIdx.x;
    const int wn   = tid >> 6;       // wave 0/1 -> n-half
    const int lane = tid & 63;
    const int lm   = lane & 15;
    const int ko   = lane >> 4;

    f32x4 acc[4][4];
    #pragma unroll
    for (int i = 0; i < 4; ++i)
        #pragma unroll
        for (int j = 0; j < 4; ++j) {
            f32x4 z = {0.f, 0.f, 0.f, 0.f};
            acc[i][j] = z;
        }

    uint4 rah[2], ral[2], rbh[4], rbl[4];
    auto load_tile = [&](int k0) {
        #pragma unroll
        for (int r = 0; r < 2; ++r) {
            int slot = r * 128 + tid;
            size_t g = (size_t)(m0 + (slot >> 2)) * KKDIM + k0 + ((slot & 3) << 3);
            rah[r] = *(const uint4*)(xhi + g);
            ral[r] = *(const uint4*)(xlo + g);
        }
        #pragma unroll
        for (int r = 0; r < 4; ++r) {
            int slot = r * 128 + tid;
            size_t g = (size_t)(n0 + (slot >> 2)) * KKDIM + k0 + ((slot & 3) << 3);
            rbh[r] = *(const uint4*)(whi + g);
            rbl[r] = *(const uint4*)(wlo + g);
        }
    };
    load_tile(0);

    for (int k0 = 0; k0 < KKDIM; k0 += 32) {
        __syncthreads();
        #pragma unroll
        for (int r = 0; r < 2; ++r) {
            int slot = r * 128 + tid;
            int idx = (slot >> 2) * LS + ((slot & 3) << 3);
            *(uint4*)&Ah[idx] = rah[r];
            *(uint4*)&Al[idx] = ral[r];
        }
        #pragma unroll
        for (int r = 0; r < 4; ++r) {
            int slot = r * 128 + tid;
            int idx = (slot >> 2) * LS + ((slot & 3) << 3);
            *(uint4*)&Bh[idx] = rbh[r];
            *(uint4*)&Bl[idx] = rbl[r];
        }
        __syncthreads();
        if (k0 + 32 < KKDIM) load_tile(k0 + 32);   // prefetch hides under MFMA

        short8 fah[4], fal[4], fbh[4], fbl[4];
        #pragma unroll
        for (int mt = 0; mt < 4; ++mt) {
            int idx = (mt * 16 + lm) * LS + ko * 8;
            fah[mt] = *(const short8*)&Ah[idx];
            fal[mt] = *(const short8*)&Al[idx];
        }
        #pragma unroll
        for (int nt = 0; nt < 4; ++nt) {
            int idx = (wn * 64 + nt * 16 + lm) * LS + ko * 8;
            fbh[nt] = *(const short8*)&Bh[idx];
            fbl[nt] = *(const short8*)&Bl[idx];
        }
        #pragma unroll
        for (int mt = 0; mt < 4; ++mt)
            #pragma unroll
            for (int nt = 0; nt < 4; ++nt) {
                f32x4 c = acc[mt][nt];
                c = __builtin_amdgcn_mfma_f32_16x16x32_bf16(fah[mt], fbh[nt], c, 0, 0, 0);
                c = __builtin_amdgcn_mfma_f32_16x16x32_bf16(fah[mt], fbl[nt], c, 0, 0, 0);
                c = __builtin_amdgcn_mfma_f32_16x16x32_bf16(fal[mt], fbh[nt], c, 0, 0, 0);
                acc[mt][nt] = c;
            }
    }

    // epilogue: bias, delta store, per-chunk (32-row) column sums
    float bs[4];
    #pragma unroll
    for (int nt = 0; nt < 4; ++nt) bs[nt] = bias[n0 + wn * 64 + nt * 16 + lm];

    float cssum[2][4] = {};
    #pragma unroll
    for (int mt = 0; mt < 4; ++mt)
        #pragma unroll
        for (int nt = 0; nt < 4; ++nt)
            #pragma unroll
            for (int r = 0; r < 4; ++r) {
                float val = acc[mt][nt][r] + bs[nt];
                int m = m0 + mt * 16 + ko * 4 + r;
                delta[(size_t)m * PP + n0 + wn * 64 + nt * 16 + lm] = val;
                cssum[mt >> 1][nt] += val;
            }
    #pragma unroll
    for (int c = 0; c < 2; ++c)
        #pragma unroll
        for (int nt = 0; nt < 4; ++nt) {
            float s = cssum[c][nt];
            s += __shfl_xor(s, 16);
            s += __shfl_xor(s, 32);
            if (lane < 16)
                csum[(size_t)(blockIdx.y * 2 + c) * PP + n0 + wn * 64 + nt * 16 + lane] = s;
        }
}

// ===========================================================================
// K2 (tier 1): Hillis-Steele exclusive scan in LDS; 2 chains per block.
// ===========================================================================
__global__ __launch_bounds__(256) void scan_lds_k(float* __restrict__ csum) {
    __shared__ float s[2][128];
    const int h = threadIdx.x >> 7, c = threadIdx.x & 127;
    const int chain = blockIdx.x * 2 + h;       // 0..1023
    const int b = chain >> 8, p = chain & 255;
    const size_t a = ((size_t)b * NCHUNK + c) * PP + p;
    s[h][c] = csum[a];
    __syncthreads();
    for (int d = 1; d < 128; d <<= 1) {
        float t = (c >= d) ? s[h][c - d] : 0.f;
        __syncthreads();
        s[h][c] += t;
        __syncthreads();
    }
    csum[a] = (c == 0) ? 0.f : s[h][c - 1];
}

// ===========================================================================
// K3 (tier 1): rotation (reg-unrolled, hw sin/cos) + passthrough copy.
// ===========================================================================
#define INV2PI 0.15915494309189535f

__global__ __launch_bounds__(256) void rotate_copy_fast_k(const float* __restrict__ delta,
                                                          const float* __restrict__ csum,
                                                          const float* __restrict__ x,
                                                          float* __restrict__ out) {
    const int bc = blockIdx.x;            // 0..511
    const int p  = threadIdx.x;
    const int tbase = bc * CHUNK;
    float d[CHUNK];
    #pragma unroll
    for (int t = 0; t < CHUNK; ++t)
        d[t] = delta[(size_t)(tbase + t) * PP + p];     // 32 independent loads
    float angle = csum[(size_t)bc * PP + p];
    float sn[CHUNK], cs[CHUNK];
    #pragma unroll
    for (int t = 0; t < CHUNK; ++t) {
        angle += d[t];
        float rev = angle * INV2PI;       // |rev| << 256: hw range ok
        sn[t] = __builtin_amdgcn_sinf(rev);
        cs[t] = __builtin_amdgcn_cosf(rev);
    }
    #pragma unroll 8
    for (int t = 0; t < CHUNK; ++t) {
        size_t row = (size_t)(tbase + t);
        float x1 = x[row * DDIM + p];
        float x2 = x[row * DDIM + PP + p];
        out[row * DDIM + p]      = x1 * cs[t] - x2 * sn[t];
        out[row * DDIM + PP + p] = x2 * cs[t] + x1 * sn[t];
    }
    // copy cols [512, 2048) for the same 32 rows
    const int half = p >> 7;
    const int q    = p & 127;
    for (int rp = 0; rp < 16; ++rp) {
        size_t row = (size_t)(tbase + rp * 2 + half);
        const float4* src = (const float4*)(x + row * DDIM + 512);
        float4*       dst = (float4*)(out + row * DDIM + 512);
        dst[q]       = src[q];
        dst[q + 128] = src[q + 128];
        dst[q + 256] = src[q + 256];
    }
}

// ===========================================================================
// Tier 2 (round-3 verified): split-bf16 MFMA GEMM w/ inline conversion.
// ===========================================================================
#define LSTR 56

__global__ __launch_bounds__(256) void gemm_mfma_k(const float* __restrict__ x,
                                                   const float* __restrict__ W,
                                                   const float* __restrict__ bias,
                                                   float* __restrict__ delta,
                                                   float* __restrict__ csum) {
    __shared__ unsigned short Ahi[128 * LSTR];
    __shared__ unsigned short Alo[128 * LSTR];
    __shared__ unsigned short Bhi[64 * LSTR];
    __shared__ unsigned short Blo[64 * LSTR];
    const int n0   = blockIdx.x * 64;
    const int m0   = blockIdx.y * 128;
    const int tid  = threadIdx.x;
    const int w    = tid >> 6;
    const int lane = tid & 63;
    const int lm   = lane & 15;
    const int ko   = lane >> 4;

    f32x4 acc[2][4];
    #pragma unroll
    for (int i = 0; i < 2; ++i)
        #pragma unroll
        for (int j = 0; j < 4; ++j) {
            f32x4 z = {0.f, 0.f, 0.f, 0.f};
            acc[i][j] = z;
        }

    for (int k0 = 0; k0 < KKDIM; k0 += 32) {
        float4 av[4], bv[2];
        #pragma unroll
        for (int r = 0; r < 4; ++r) {
            int f = r * 256 + tid;
            av[r] = *(const float4*)(x + (size_t)(m0 + (f >> 3)) * KKDIM + k0 + ((f & 7) << 2));
        }
        #pragma unroll
        for (int r = 0; r < 2; ++r) {
            int f = r * 256 + tid;
            bv[r] = *(const float4*)(W + (size_t)(n0 + (f >> 3)) * KKDIM + k0 + ((f & 7) << 2));
        }
        __syncthreads();
        #pragma unroll
        for (int r = 0; r < 4; ++r) {
            int f = r * 256 + tid;
            int idx = (f >> 3) * LSTR + ((f & 7) << 2);
            float4 v = av[r];
            unsigned short h0 = f2bf(v.x), h1 = f2bf(v.y), h2 = f2bf(v.z), h3 = f2bf(v.w);
            unsigned short l0 = f2bf(v.x - bf2f(h0)), l1 = f2bf(v.y - bf2f(h1));
            unsigned short l2 = f2bf(v.z - bf2f(h2)), l3 = f2bf(v.w - bf2f(h3));
            uint2 hp = { (unsigned)h0 | ((unsigned)h1 << 16), (unsigned)h2 | ((unsigned)h3 << 16) };
            uint2 lp = { (unsigned)l0 | ((unsigned)l1 << 16), (unsigned)l2 | ((unsigned)l3 << 16) };
            *(uint2*)&Ahi[idx] = hp;
            *(uint2*)&Alo[idx] = lp;
        }
        #pragma unroll
        for (int r = 0; r < 2; ++r) {
            int f = r * 256 + tid;
            int idx = (f >> 3) * LSTR + ((f & 7) << 2);
            float4 v = bv[r];
            unsigned short h0 = f2bf(v.x), h1 = f2bf(v.y), h2 = f2bf(v.z), h3 = f2bf(v.w);
            unsigned short l0 = f2bf(v.x - bf2f(h0)), l1 = f2bf(v.y - bf2f(h1));
            unsigned short l2 = f2bf(v.z - bf2f(h2)), l3 = f2bf(v.w - bf2f(h3));
            uint2 hp = { (unsigned)h0 | ((unsigned)h1 << 16), (unsigned)h2 | ((unsigned)h3 << 16) };
            uint2 lp = { (unsigned)l0 | ((unsigned)l1 << 16), (unsigned)l2 | ((unsigned)l3 << 16) };
            *(uint2*)&Bhi[idx] = hp;
            *(uint2*)&Blo[idx] = lp;
        }
        __syncthreads();
        short8 ah[2], al[2], bh[4], bl[4];
        #pragma unroll
        for (int mt = 0; mt < 2; ++mt) {
            int idx = (w * 32 + mt * 16 + lm) * LSTR + ko * 8;
            ah[mt] = *(const short8*)&Ahi[idx];
            al[mt] = *(const short8*)&Alo[idx];
        }
        #pragma unroll
        for (int nt = 0; nt < 4; ++nt) {
            int idx = (nt * 16 + lm) * LSTR + ko * 8;
            bh[nt] = *(const short8*)&Bhi[idx];
            bl[nt] = *(const short8*)&Blo[idx];
        }
        #pragma unroll
        for (int mt = 0; mt < 2; ++mt)
            #pragma unroll
            for (int nt = 0; nt < 4; ++nt) {
                f32x4 c = acc[mt][nt];
                c = __builtin_amdgcn_mfma_f32_16x16x32_bf16(ah[mt], bh[nt], c, 0, 0, 0);
                c = __builtin_amdgcn_mfma_f32_16x16x32_bf16(ah[mt], bl[nt], c, 0, 0, 0);
                c = __builtin_amdgcn_mfma_f32_16x16x32_bf16(al[mt], bh[nt], c, 0, 0, 0);
                acc[mt][nt] = c;
            }
    }

    float bsv[4];
    #pragma unroll
    for (int nt = 0; nt < 4; ++nt) bsv[nt] = bias[n0 + nt * 16 + lm];
    float cs[4] = {0.f, 0.f, 0.f, 0.f};
    #pragma unroll
    for (int mt = 0; mt < 2; ++mt)
        #pragma unroll
        for (int nt = 0; nt < 4; ++nt)
            #pragma unroll
            for (int r = 0; r < 4; ++r) {
                float val = acc[mt][nt][r] + bsv[nt];
                int m = m0 + w * 32 + mt * 16 + ko * 4 + r;
                delta[(size_t)m * PP + n0 + nt * 16 + lm] = val;
                cs[nt] += val;
            }
    #pragma unroll
    for (int nt = 0; nt < 4; ++nt) {
        float s = cs[nt];
        s += __shfl_xor(s, 16);
        s += __shfl_xor(s, 32);
        if (lane < 16)
            csum[(size_t)(m0 / CHUNK + w) * PP + n0 + nt * 16 + lane] = s;
    }
}

__global__ __launch_bounds__(256) void scan_k(float* __restrict__ csum, int cstride) {
    const int idx = blockIdx.x * 256 + threadIdx.x;
    const int b = idx >> 8;
    const int p = idx & 255;
    float run = 0.f;
    for (int c0 = 0; c0 < NCHUNK; c0 += 8) {
        float v[8];
        #pragma unroll
        for (int j = 0; j < 8; ++j)
            v[j] = csum[(size_t)(b * NCHUNK + c0 + j) * cstride + p];
        #pragma unroll
        for (int j = 0; j < 8; ++j) {
            float t = v[j];
            csum[(size_t)(b * NCHUNK + c0 + j) * cstride + p] = run;
            run += t;
        }
    }
}

__global__ __launch_bounds__(256) void rotate_copy_k(const float* __restrict__ delta,
                                                     const float* __restrict__ csum,
                                                     const float* __restrict__ x,
                                                     float* __restrict__ out) {
    const int bc = blockIdx.x;
    const int p  = threadIdx.x;
    const int tbase = bc * CHUNK;
    float angle = csum[(size_t)bc * PP + p];
    for (int t = 0; t < CHUNK; ++t) {
        size_t row = (size_t)(tbase + t);
        angle += delta[row * PP + p];
        float s, co;
        sincosf(angle, &s, &co);
        float x1 = x[row * DDIM + p];
        float x2 = x[row * DDIM + PP + p];
        out[row * DDIM + p]      = x1 * co - x2 * s;
        out[row * DDIM + PP + p] = x2 * co + x1 * s;
    }
    const int half = p >> 7;
    const int q    = p & 127;
    for (int rp = 0; rp < 16; ++rp) {
        size_t row = (size_t)(tbase + rp * 2 + half);
        const float4* src = (const float4*)(x + row * DDIM + 512);
        float4*       dst = (float4*)(out + row * DDIM + 512);
        dst[q]       = src[q];
        dst[q + 128] = src[q + 128];
        dst[q + 256] = src[q + 256];
    }
}

// ===========================================================================
// Tier 3 (round-2 verified): fp32 pipeline staging in d_out.
// ===========================================================================
__global__ __launch_bounds__(256) void gemm_k(const float* __restrict__ x,
                                              const float* __restrict__ W,
                                              const float* __restrict__ bias,
                                              float* __restrict__ delta,
                                              int dstride, int doff) {
    __shared__ float As[16][68];
    __shared__ float Bs[16][68];
    const int m0  = blockIdx.x * 64;
    const int n0  = blockIdx.y * 64;
    const int tid = threadIdx.x;
    const int lr  = tid >> 2;
    const int lc  = (tid & 3) << 2;
    const int tmi = tid & 15;
    const int tni = tid >> 4;
    float acc[4][4] = {};
    for (int k0 = 0; k0 < KKDIM; k0 += 16) {
        float4 a4 = *(const float4*)(x + (size_t)(m0 + lr) * KKDIM + k0 + lc);
        float4 b4 = *(const float4*)(W + (size_t)(n0 + lr) * KKDIM + k0 + lc);
        __syncthreads();
        As[lc + 0][lr] = a4.x; As[lc + 1][lr] = a4.y;
        As[lc + 2][lr] = a4.z; As[lc + 3][lr] = a4.w;
        Bs[lc + 0][lr] = b4.x; Bs[lc + 1][lr] = b4.y;
        Bs[lc + 2][lr] = b4.z; Bs[lc + 3][lr] = b4.w;
        __syncthreads();
        #pragma unroll
        for (int kk = 0; kk < 16; ++kk) {
            float4 av = *(const float4*)&As[kk][tmi * 4];
            float4 bv = *(const float4*)&Bs[kk][tni * 4];
            float am[4] = {av.x, av.y, av.z, av.w};
            float bn[4] = {bv.x, bv.y, bv.z, bv.w};
            #pragma unroll
            for (int i = 0; i < 4; ++i)
                #pragma unroll
                for (int j = 0; j < 4; ++j)
                    acc[i][j] += am[i] * bn[j];
        }
    }
    const float4 b4 = *(const float4*)(bias + n0 + tni * 4);
    #pragma unroll
    for (int i = 0; i < 4; ++i) {
        size_t m = (size_t)(m0 + tmi * 4 + i);
        float4 o;
        o.x = acc[i][0] + b4.x; o.y = acc[i][1] + b4.y;
        o.z = acc[i][2] + b4.z; o.w = acc[i][3] + b4.w;
        *(float4*)(delta + m * dstride + doff + n0 + tni * 4) = o;
    }
}

__global__ __launch_bounds__(256) void chunksum_k(const float* __restrict__ delta,
                                                  int dstride, int doff,
                                                  float* __restrict__ csum, int cstride) {
    const int bc = blockIdx.x;
    const int b  = bc / NCHUNK;
    const int c  = bc % NCHUNK;
    const int p  = threadIdx.x;
    const int tbase = b * TT + c * CHUNK;
    float s = 0.f;
    #pragma unroll 8
    for (int t = 0; t < CHUNK; ++t)
        s += delta[(size_t)(tbase + t) * dstride + doff + p];
    csum[(size_t)bc * cstride + p] = s;
}

__global__ __launch_bounds__(256) void rotate_k(const float* __restrict__ delta,
                                                int dstride, int doff,
                                                const float* __restrict__ csum, int cstride,
                                                const float* __restrict__ x,
                                                float* __restrict__ out) {
    const int bc = blockIdx.x;
    const int b  = bc / NCHUNK;
    const int c  = bc % NCHUNK;
    const int p  = threadIdx.x;
    const int tbase = b * TT + c * CHUNK;
    float angle = csum[(size_t)bc * cstride + p];
    for (int t = 0; t < CHUNK; ++t) {
        size_t row = (size_t)(tbase + t);
        angle += delta[row * dstride + doff + p];
        float s, co;
        sincosf(angle, &s, &co);
        float x1 = x[row * DDIM + p];
        float x2 = x[row * DDIM + PP + p];
        out[row * DDIM + p]      = x1 * co - x2 * s;
        out[row * DDIM + PP + p] = x2 * co + x1 * s;
    }
}

__global__ __launch_bounds__(256) void copy_k(const float* __restrict__ x,
                                              float* __restrict__ out) {
    const size_t row = (size_t)blockIdx.x * 4 + (threadIdx.x >> 6);
    const int lane = threadIdx.x & 63;
    const int col = 512 + (blockIdx.y * 64 + lane) * 4;
    const size_t a = row * DDIM + col;
    *(float4*)(out + a) = *(const float4*)(x + a);
}

extern "C" void kernel_launch(void* const* d_in, const int* in_sizes, int n_in,
                              void* d_out, int out_size, void* d_ws, size_t ws_size,
                              hipStream_t stream) {
    const float* x    = (const float*)d_in[0];
    const float* W    = (const float*)d_in[1];
    const float* bias = (const float*)d_in[2];
    float* out = (float*)d_out;

    const size_t delta_elems = (size_t)MM * PP;          // 4.19M fp32
    const size_t csum_elems  = (size_t)BB * NCHUNK * PP; // 131K fp32
    const size_t x_elems     = (size_t)MM * KKDIM;       // 33.55M
    const size_t w_elems     = (size_t)PP * KKDIM;       // 524K
    const size_t need2 = (delta_elems + csum_elems) * sizeof(float);
    const size_t need1 = need2 + (2 * x_elems + 2 * w_elems) * sizeof(unsigned short);

    if (ws_size >= need1) {
        float* delta = (float*)d_ws;
        float* csum  = delta + delta_elems;
        unsigned short* xhi = (unsigned short*)(csum + csum_elems);
        unsigned short* xlo = xhi + x_elems;
        unsigned short* whi = xlo + x_elems;
        unsigned short* wlo = whi + w_elems;
        cvt_k<<<x_elems / 1024, 256, 0, stream>>>(x, xhi, xlo);
        cvt_k<<<w_elems / 1024, 256, 0, stream>>>(W, whi, wlo);
        gemm_bf16_k<<<dim3(PP / 128, MM / 64), 128, 0, stream>>>(xhi, xlo, whi, wlo, bias, delta, csum);
        scan_lds_k<<<(BB * PP) / 2, 256, 0, stream>>>(csum);
        rotate_copy_fast_k<<<BB * NCHUNK, 256, 0, stream>>>(delta, csum, x, out);
    } else if (ws_size >= need2) {
        float* delta = (float*)d_ws;
        float* csum  = delta + delta_elems;
        gemm_mfma_k<<<dim3(PP / 64, MM / 128), 256, 0, stream>>>(x, W, bias, delta, csum);
        scan_k<<<(BB * PP) / 256, 256, 0, stream>>>(csum, PP);
        rotate_copy_k<<<BB * NCHUNK, 256, 0, stream>>>(delta, csum, x, out);
    } else {
        float* delta = out; const int dstride = DDIM, doff = 512;
        float* csum  = out + 768; const int cstride = DDIM;
        gemm_k<<<dim3(MM / 64, PP / 64), 256, 0, stream>>>(x, W, bias, delta, dstride, doff);
        chunksum_k<<<BB * NCHUNK, 256, 0, stream>>>(delta, dstride, doff, csum, cstride);
        scan_k<<<(BB * PP) / 256, 256, 0, stream>>>(csum, cstride);
        rotate_k<<<BB * NCHUNK, 256, 0, stream>>>(delta, dstride, doff, csum, cstride, x, out);
        copy_k<<<dim3(MM / 4, 6), 256, 0, stream>>>(x, out);
    }
}

// Round 5
// 409.547 us; speedup vs baseline: 1.3404x; 1.3404x over previous
//
#include <hip/hip_runtime.h>
#include <math.h>

#define BB 4
#define TT 4096
#define DDIM 2048
#define PP 256                 // DD_PAIRS
#define MM (BB*TT)             // 16384 rows
#define KKDIM 2048
#define CHUNK 32
#define NCHUNK (TT/CHUNK)      // 128

typedef __attribute__((ext_vector_type(8))) short short8;   // 8 bf16 (4 VGPRs)
typedef __attribute__((ext_vector_type(4))) float f32x4;    // MFMA C/D

__device__ __forceinline__ unsigned short f2bf(float f) {
    unsigned u = __float_as_uint(f);
    u += 0x7FFF + ((u >> 16) & 1);          // round-to-nearest-even
    return (unsigned short)(u >> 16);
}
__device__ __forceinline__ float bf2f(unsigned short h) {
    return __uint_as_float(((unsigned)h) << 16);
}

// ===========================================================================
// K0: fp32 -> (hi, lo) bf16 split (used for W only in tier 1).
// ===========================================================================
__global__ __launch_bounds__(256) void cvt_k(const float* __restrict__ src,
                                             unsigned short* __restrict__ hi,
                                             unsigned short* __restrict__ lo) {
    size_t i = ((size_t)blockIdx.x * 256 + threadIdx.x) * 4;
    float4 v = *(const float4*)(src + i);
    unsigned short h0 = f2bf(v.x), h1 = f2bf(v.y), h2 = f2bf(v.z), h3 = f2bf(v.w);
    unsigned short l0 = f2bf(v.x - bf2f(h0)), l1 = f2bf(v.y - bf2f(h1));
    unsigned short l2 = f2bf(v.z - bf2f(h2)), l3 = f2bf(v.w - bf2f(h3));
    uint2 hp = { (unsigned)h0 | ((unsigned)h1 << 16), (unsigned)h2 | ((unsigned)h3 << 16) };
    uint2 lp = { (unsigned)l0 | ((unsigned)l1 << 16), (unsigned)l2 | ((unsigned)l3 << 16) };
    *(uint2*)(hi + i) = hp;
    *(uint2*)(lo + i) = lp;
}

// ===========================================================================
// K1 (tier 1): split-bf16 MFMA GEMM, block = 64M x 256N (ALL of N), BK=32.
// 256 threads = 4 waves; wave w owns n in [64w, 64w+64), all 64 m (mt=nt=4).
// x converted fp32->hi/lo exactly ONCE (N not tiled); W hi/lo precomputed.
// LDS stride 40 shorts (80 B): every access pattern is exactly 2-way (free).
// Fused per-chunk (32-row) column sums in the epilogue.
// ===========================================================================
#define LS 40

__global__ __launch_bounds__(256) void gemm_n256_k(
        const float* __restrict__ x,
        const unsigned short* __restrict__ whi, const unsigned short* __restrict__ wlo,
        const float* __restrict__ bias,
        float* __restrict__ delta, float* __restrict__ csum) {
    __shared__ unsigned short Ah[64 * LS],  Al[64 * LS];    // 5 KB each
    __shared__ unsigned short Bh[256 * LS], Bl[256 * LS];   // 20 KB each
    const int m0   = blockIdx.x * 64;
    const int tid  = threadIdx.x;
    const int w    = tid >> 6;       // wave 0..3 -> n quarter
    const int lane = tid & 63;
    const int lm   = lane & 15;
    const int ko   = lane >> 4;
    const int srow = tid >> 2;       // staging row 0..63
    const int skc  = (tid & 3) << 3; // staging k-offset in shorts {0,8,16,24}

    f32x4 acc[4][4];
    #pragma unroll
    for (int i = 0; i < 4; ++i)
        #pragma unroll
        for (int j = 0; j < 4; ++j) {
            f32x4 z = {0.f, 0.f, 0.f, 0.f};
            acc[i][j] = z;
        }

    float4 ra0, ra1;           // next A: 8 floats
    uint4 rbh[4], rbl[4];      // next B: 4 rows' worth of 8 shorts
    auto load_tile = [&](int k0) {
        const float* ap = x + (size_t)(m0 + srow) * KKDIM + k0 + skc;
        ra0 = *(const float4*)ap;
        ra1 = *(const float4*)(ap + 4);
        #pragma unroll
        for (int r = 0; r < 4; ++r) {
            size_t g = (size_t)(r * 64 + srow) * KKDIM + k0 + skc;
            rbh[r] = *(const uint4*)(whi + g);
            rbl[r] = *(const uint4*)(wlo + g);
        }
    };
    load_tile(0);

    for (int k0 = 0; k0 < KKDIM; k0 += 32) {
        __syncthreads();   // prior iter's fragment reads complete
        {
            // convert A regs -> hi/lo, store
            float vv[8] = {ra0.x, ra0.y, ra0.z, ra0.w, ra1.x, ra1.y, ra1.z, ra1.w};
            unsigned short h[8], l[8];
            #pragma unroll
            for (int j = 0; j < 8; ++j) {
                h[j] = f2bf(vv[j]);
                l[j] = f2bf(vv[j] - bf2f(h[j]));
            }
            uint4 hp = { (unsigned)h[0] | ((unsigned)h[1] << 16), (unsigned)h[2] | ((unsigned)h[3] << 16),
                         (unsigned)h[4] | ((unsigned)h[5] << 16), (unsigned)h[6] | ((unsigned)h[7] << 16) };
            uint4 lp = { (unsigned)l[0] | ((unsigned)l[1] << 16), (unsigned)l[2] | ((unsigned)l[3] << 16),
                         (unsigned)l[4] | ((unsigned)l[5] << 16), (unsigned)l[6] | ((unsigned)l[7] << 16) };
            int idx = srow * LS + skc;
            *(uint4*)&Ah[idx] = hp;
            *(uint4*)&Al[idx] = lp;
            #pragma unroll
            for (int r = 0; r < 4; ++r) {
                int bidx = (r * 64 + srow) * LS + skc;
                *(uint4*)&Bh[bidx] = rbh[r];
                *(uint4*)&Bl[bidx] = rbl[r];
            }
        }
        __syncthreads();
        if (k0 + 32 < KKDIM) load_tile(k0 + 32);   // global prefetch drains under MFMA

        short8 fah[4], fal[4], fbh[4], fbl[4];
        #pragma unroll
        for (int mt = 0; mt < 4; ++mt) {
            int idx = (mt * 16 + lm) * LS + ko * 8;
            fah[mt] = *(const short8*)&Ah[idx];
            fal[mt] = *(const short8*)&Al[idx];
        }
        #pragma unroll
        for (int nt = 0; nt < 4; ++nt) {
            int idx = (w * 64 + nt * 16 + lm) * LS + ko * 8;
            fbh[nt] = *(const short8*)&Bh[idx];
            fbl[nt] = *(const short8*)&Bl[idx];
        }
        #pragma unroll
        for (int mt = 0; mt < 4; ++mt)
            #pragma unroll
            for (int nt = 0; nt < 4; ++nt) {
                f32x4 c = acc[mt][nt];
                c = __builtin_amdgcn_mfma_f32_16x16x32_bf16(fah[mt], fbh[nt], c, 0, 0, 0);
                c = __builtin_amdgcn_mfma_f32_16x16x32_bf16(fah[mt], fbl[nt], c, 0, 0, 0);
                c = __builtin_amdgcn_mfma_f32_16x16x32_bf16(fal[mt], fbh[nt], c, 0, 0, 0);
                acc[mt][nt] = c;
            }
    }

    // epilogue: bias, delta store, per-chunk column sums (2 chunks per tile)
    float bs[4];
    #pragma unroll
    for (int nt = 0; nt < 4; ++nt) bs[nt] = bias[w * 64 + nt * 16 + lm];

    float cssum[2][4] = {};
    #pragma unroll
    for (int mt = 0; mt < 4; ++mt)
        #pragma unroll
        for (int nt = 0; nt < 4; ++nt)
            #pragma unroll
            for (int r = 0; r < 4; ++r) {
                float val = acc[mt][nt][r] + bs[nt];
                int m = m0 + mt * 16 + ko * 4 + r;
                delta[(size_t)m * PP + w * 64 + nt * 16 + lm] = val;
                cssum[mt >> 1][nt] += val;
            }
    #pragma unroll
    for (int c = 0; c < 2; ++c)
        #pragma unroll
        for (int nt = 0; nt < 4; ++nt) {
            float s = cssum[c][nt];
            s += __shfl_xor(s, 16);
            s += __shfl_xor(s, 32);
            if (lane < 16)
                csum[(size_t)(blockIdx.x * 2 + c) * PP + w * 64 + nt * 16 + lane] = s;
        }
}

// ===========================================================================
// K2 (tier 1): Hillis-Steele exclusive scan in LDS; 2 chains per block.
// ===========================================================================
__global__ __launch_bounds__(256) void scan_lds_k(float* __restrict__ csum) {
    __shared__ float s[2][128];
    const int h = threadIdx.x >> 7, c = threadIdx.x & 127;
    const int chain = blockIdx.x * 2 + h;       // 0..1023
    const int b = chain >> 8, p = chain & 255;
    const size_t a = ((size_t)b * NCHUNK + c) * PP + p;
    s[h][c] = csum[a];
    __syncthreads();
    for (int d = 1; d < 128; d <<= 1) {
        float t = (c >= d) ? s[h][c - d] : 0.f;
        __syncthreads();
        s[h][c] += t;
        __syncthreads();
    }
    csum[a] = (c == 0) ? 0.f : s[h][c - 1];
}

// ===========================================================================
// K3 (tier 1): rotation (two 16-row batches, hw sin/cos) + passthrough copy.
// ===========================================================================
#define INV2PI 0.15915494309189535f

__global__ __launch_bounds__(256) void rotate_copy2_k(const float* __restrict__ delta,
                                                      const float* __restrict__ csum,
                                                      const float* __restrict__ x,
                                                      float* __restrict__ out) {
    const int bc = blockIdx.x;            // 0..511
    const int p  = threadIdx.x;
    const int tbase = bc * CHUNK;
    float angle = csum[(size_t)bc * PP + p];
    #pragma unroll
    for (int g = 0; g < 2; ++g) {
        float d[16];
        #pragma unroll
        for (int t = 0; t < 16; ++t)
            d[t] = delta[(size_t)(tbase + g * 16 + t) * PP + p];   // independent loads
        float sn[16], cs[16];
        #pragma unroll
        for (int t = 0; t < 16; ++t) {
            angle += d[t];
            float rev = angle * INV2PI;       // |rev| < ~40: hw range ok
            sn[t] = __builtin_amdgcn_sinf(rev);
            cs[t] = __builtin_amdgcn_cosf(rev);
        }
        #pragma unroll 4
        for (int t = 0; t < 16; ++t) {
            size_t row = (size_t)(tbase + g * 16 + t);
            float x1 = x[row * DDIM + p];
            float x2 = x[row * DDIM + PP + p];
            out[row * DDIM + p]      = x1 * cs[t] - x2 * sn[t];
            out[row * DDIM + PP + p] = x2 * cs[t] + x1 * sn[t];
        }
    }
    // copy cols [512, 2048) for the same 32 rows
    const int half = p >> 7;
    const int q    = p & 127;
    for (int rp = 0; rp < 16; ++rp) {
        size_t row = (size_t)(tbase + rp * 2 + half);
        const float4* src = (const float4*)(x + row * DDIM + 512);
        float4*       dst = (float4*)(out + row * DDIM + 512);
        dst[q]       = src[q];
        dst[q + 128] = src[q + 128];
        dst[q + 256] = src[q + 256];
    }
}

// ===========================================================================
// Tier 2 (round-3 verified, 368 us total): inline-convert split-bf16 GEMM.
// ===========================================================================
#define LSTR 56

__global__ __launch_bounds__(256) void gemm_mfma_k(const float* __restrict__ x,
                                                   const float* __restrict__ W,
                                                   const float* __restrict__ bias,
                                                   float* __restrict__ delta,
                                                   float* __restrict__ csum) {
    __shared__ unsigned short Ahi[128 * LSTR];
    __shared__ unsigned short Alo[128 * LSTR];
    __shared__ unsigned short Bhi[64 * LSTR];
    __shared__ unsigned short Blo[64 * LSTR];
    const int n0   = blockIdx.x * 64;
    const int m0   = blockIdx.y * 128;
    const int tid  = threadIdx.x;
    const int w    = tid >> 6;
    const int lane = tid & 63;
    const int lm   = lane & 15;
    const int ko   = lane >> 4;

    f32x4 acc[2][4];
    #pragma unroll
    for (int i = 0; i < 2; ++i)
        #pragma unroll
        for (int j = 0; j < 4; ++j) {
            f32x4 z = {0.f, 0.f, 0.f, 0.f};
            acc[i][j] = z;
        }

    for (int k0 = 0; k0 < KKDIM; k0 += 32) {
        float4 av[4], bv[2];
        #pragma unroll
        for (int r = 0; r < 4; ++r) {
            int f = r * 256 + tid;
            av[r] = *(const float4*)(x + (size_t)(m0 + (f >> 3)) * KKDIM + k0 + ((f & 7) << 2));
        }
        #pragma unroll
        for (int r = 0; r < 2; ++r) {
            int f = r * 256 + tid;
            bv[r] = *(const float4*)(W + (size_t)(n0 + (f >> 3)) * KKDIM + k0 + ((f & 7) << 2));
        }
        __syncthreads();
        #pragma unroll
        for (int r = 0; r < 4; ++r) {
            int f = r * 256 + tid;
            int idx = (f >> 3) * LSTR + ((f & 7) << 2);
            float4 v = av[r];
            unsigned short h0 = f2bf(v.x), h1 = f2bf(v.y), h2 = f2bf(v.z), h3 = f2bf(v.w);
            unsigned short l0 = f2bf(v.x - bf2f(h0)), l1 = f2bf(v.y - bf2f(h1));
            unsigned short l2 = f2bf(v.z - bf2f(h2)), l3 = f2bf(v.w - bf2f(h3));
            uint2 hp = { (unsigned)h0 | ((unsigned)h1 << 16), (unsigned)h2 | ((unsigned)h3 << 16) };
            uint2 lp = { (unsigned)l0 | ((unsigned)l1 << 16), (unsigned)l2 | ((unsigned)l3 << 16) };
            *(uint2*)&Ahi[idx] = hp;
            *(uint2*)&Alo[idx] = lp;
        }
        #pragma unroll
        for (int r = 0; r < 2; ++r) {
            int f = r * 256 + tid;
            int idx = (f >> 3) * LSTR + ((f & 7) << 2);
            float4 v = bv[r];
            unsigned short h0 = f2bf(v.x), h1 = f2bf(v.y), h2 = f2bf(v.z), h3 = f2bf(v.w);
            unsigned short l0 = f2bf(v.x - bf2f(h0)), l1 = f2bf(v.y - bf2f(h1));
            unsigned short l2 = f2bf(v.z - bf2f(h2)), l3 = f2bf(v.w - bf2f(h3));
            uint2 hp = { (unsigned)h0 | ((unsigned)h1 << 16), (unsigned)h2 | ((unsigned)h3 << 16) };
            uint2 lp = { (unsigned)l0 | ((unsigned)l1 << 16), (unsigned)l2 | ((unsigned)l3 << 16) };
            *(uint2*)&Bhi[idx] = hp;
            *(uint2*)&Blo[idx] = lp;
        }
        __syncthreads();
        short8 ah[2], al[2], bh[4], bl[4];
        #pragma unroll
        for (int mt = 0; mt < 2; ++mt) {
            int idx = (w * 32 + mt * 16 + lm) * LSTR + ko * 8;
            ah[mt] = *(const short8*)&Ahi[idx];
            al[mt] = *(const short8*)&Alo[idx];
        }
        #pragma unroll
        for (int nt = 0; nt < 4; ++nt) {
            int idx = (nt * 16 + lm) * LSTR + ko * 8;
            bh[nt] = *(const short8*)&Bhi[idx];
            bl[nt] = *(const short8*)&Blo[idx];
        }
        #pragma unroll
        for (int mt = 0; mt < 2; ++mt)
            #pragma unroll
            for (int nt = 0; nt < 4; ++nt) {
                f32x4 c = acc[mt][nt];
                c = __builtin_amdgcn_mfma_f32_16x16x32_bf16(ah[mt], bh[nt], c, 0, 0, 0);
                c = __builtin_amdgcn_mfma_f32_16x16x32_bf16(ah[mt], bl[nt], c, 0, 0, 0);
                c = __builtin_amdgcn_mfma_f32_16x16x32_bf16(al[mt], bh[nt], c, 0, 0, 0);
                acc[mt][nt] = c;
            }
    }

    float bsv[4];
    #pragma unroll
    for (int nt = 0; nt < 4; ++nt) bsv[nt] = bias[n0 + nt * 16 + lm];
    float cs[4] = {0.f, 0.f, 0.f, 0.f};
    #pragma unroll
    for (int mt = 0; mt < 2; ++mt)
        #pragma unroll
        for (int nt = 0; nt < 4; ++nt)
            #pragma unroll
            for (int r = 0; r < 4; ++r) {
                float val = acc[mt][nt][r] + bsv[nt];
                int m = m0 + w * 32 + mt * 16 + ko * 4 + r;
                delta[(size_t)m * PP + n0 + nt * 16 + lm] = val;
                cs[nt] += val;
            }
    #pragma unroll
    for (int nt = 0; nt < 4; ++nt) {
        float s = cs[nt];
        s += __shfl_xor(s, 16);
        s += __shfl_xor(s, 32);
        if (lane < 16)
            csum[(size_t)(m0 / CHUNK + w) * PP + n0 + nt * 16 + lane] = s;
    }
}

__global__ __launch_bounds__(256) void scan_k(float* __restrict__ csum, int cstride) {
    const int idx = blockIdx.x * 256 + threadIdx.x;
    const int b = idx >> 8;
    const int p = idx & 255;
    float run = 0.f;
    for (int c0 = 0; c0 < NCHUNK; c0 += 8) {
        float v[8];
        #pragma unroll
        for (int j = 0; j < 8; ++j)
            v[j] = csum[(size_t)(b * NCHUNK + c0 + j) * cstride + p];
        #pragma unroll
        for (int j = 0; j < 8; ++j) {
            float t = v[j];
            csum[(size_t)(b * NCHUNK + c0 + j) * cstride + p] = run;
            run += t;
        }
    }
}

__global__ __launch_bounds__(256) void rotate_copy_k(const float* __restrict__ delta,
                                                     const float* __restrict__ csum,
                                                     const float* __restrict__ x,
                                                     float* __restrict__ out) {
    const int bc = blockIdx.x;
    const int p  = threadIdx.x;
    const int tbase = bc * CHUNK;
    float angle = csum[(size_t)bc * PP + p];
    for (int t = 0; t < CHUNK; ++t) {
        size_t row = (size_t)(tbase + t);
        angle += delta[row * PP + p];
        float s, co;
        sincosf(angle, &s, &co);
        float x1 = x[row * DDIM + p];
        float x2 = x[row * DDIM + PP + p];
        out[row * DDIM + p]      = x1 * co - x2 * s;
        out[row * DDIM + PP + p] = x2 * co + x1 * s;
    }
    const int half = p >> 7;
    const int q    = p & 127;
    for (int rp = 0; rp < 16; ++rp) {
        size_t row = (size_t)(tbase + rp * 2 + half);
        const float4* src = (const float4*)(x + row * DDIM + 512);
        float4*       dst = (float4*)(out + row * DDIM + 512);
        dst[q]       = src[q];
        dst[q + 128] = src[q + 128];
        dst[q + 256] = src[q + 256];
    }
}

// ===========================================================================
// Tier 3 (round-2 verified): fp32 pipeline staging in d_out.
// ===========================================================================
__global__ __launch_bounds__(256) void gemm_k(const float* __restrict__ x,
                                              const float* __restrict__ W,
                                              const float* __restrict__ bias,
                                              float* __restrict__ delta,
                                              int dstride, int doff) {
    __shared__ float As[16][68];
    __shared__ float Bs[16][68];
    const int m0  = blockIdx.x * 64;
    const int n0  = blockIdx.y * 64;
    const int tid = threadIdx.x;
    const int lr  = tid >> 2;
    const int lc  = (tid & 3) << 2;
    const int tmi = tid & 15;
    const int tni = tid >> 4;
    float acc[4][4] = {};
    for (int k0 = 0; k0 < KKDIM; k0 += 16) {
        float4 a4 = *(const float4*)(x + (size_t)(m0 + lr) * KKDIM + k0 + lc);
        float4 b4 = *(const float4*)(W + (size_t)(n0 + lr) * KKDIM + k0 + lc);
        __syncthreads();
        As[lc + 0][lr] = a4.x; As[lc + 1][lr] = a4.y;
        As[lc + 2][lr] = a4.z; As[lc + 3][lr] = a4.w;
        Bs[lc + 0][lr] = b4.x; Bs[lc + 1][lr] = b4.y;
        Bs[lc + 2][lr] = b4.z; Bs[lc + 3][lr] = b4.w;
        __syncthreads();
        #pragma unroll
        for (int kk = 0; kk < 16; ++kk) {
            float4 av = *(const float4*)&As[kk][tmi * 4];
            float4 bv = *(const float4*)&Bs[kk][tni * 4];
            float am[4] = {av.x, av.y, av.z, av.w};
            float bn[4] = {bv.x, bv.y, bv.z, bv.w};
            #pragma unroll
            for (int i = 0; i < 4; ++i)
                #pragma unroll
                for (int j = 0; j < 4; ++j)
                    acc[i][j] += am[i] * bn[j];
        }
    }
    const float4 b4 = *(const float4*)(bias + n0 + tni * 4);
    #pragma unroll
    for (int i = 0; i < 4; ++i) {
        size_t m = (size_t)(m0 + tmi * 4 + i);
        float4 o;
        o.x = acc[i][0] + b4.x; o.y = acc[i][1] + b4.y;
        o.z = acc[i][2] + b4.z; o.w = acc[i][3] + b4.w;
        *(float4*)(delta + m * dstride + doff + n0 + tni * 4) = o;
    }
}

__global__ __launch_bounds__(256) void chunksum_k(const float* __restrict__ delta,
                                                  int dstride, int doff,
                                                  float* __restrict__ csum, int cstride) {
    const int bc = blockIdx.x;
    const int b  = bc / NCHUNK;
    const int c  = bc % NCHUNK;
    const int p  = threadIdx.x;
    const int tbase = b * TT + c * CHUNK;
    float s = 0.f;
    #pragma unroll 8
    for (int t = 0; t < CHUNK; ++t)
        s += delta[(size_t)(tbase + t) * dstride + doff + p];
    csum[(size_t)bc * cstride + p] = s;
}

__global__ __launch_bounds__(256) void rotate_k(const float* __restrict__ delta,
                                                int dstride, int doff,
                                                const float* __restrict__ csum, int cstride,
                                                const float* __restrict__ x,
                                                float* __restrict__ out) {
    const int bc = blockIdx.x;
    const int b  = bc / NCHUNK;
    const int c  = bc % NCHUNK;
    const int p  = threadIdx.x;
    const int tbase = b * TT + c * CHUNK;
    float angle = csum[(size_t)bc * cstride + p];
    for (int t = 0; t < CHUNK; ++t) {
        size_t row = (size_t)(tbase + t);
        angle += delta[row * dstride + doff + p];
        float s, co;
        sincosf(angle, &s, &co);
        float x1 = x[row * DDIM + p];
        float x2 = x[row * DDIM + PP + p];
        out[row * DDIM + p]      = x1 * co - x2 * s;
        out[row * DDIM + PP + p] = x2 * co + x1 * s;
    }
}

__global__ __launch_bounds__(256) void copy_k(const float* __restrict__ x,
                                              float* __restrict__ out) {
    const size_t row = (size_t)blockIdx.x * 4 + (threadIdx.x >> 6);
    const int lane = threadIdx.x & 63;
    const int col = 512 + (blockIdx.y * 64 + lane) * 4;
    const size_t a = row * DDIM + col;
    *(float4*)(out + a) = *(const float4*)(x + a);
}

extern "C" void kernel_launch(void* const* d_in, const int* in_sizes, int n_in,
                              void* d_out, int out_size, void* d_ws, size_t ws_size,
                              hipStream_t stream) {
    const float* x    = (const float*)d_in[0];
    const float* W    = (const float*)d_in[1];
    const float* bias = (const float*)d_in[2];
    float* out = (float*)d_out;

    const size_t delta_elems = (size_t)MM * PP;          // 4.19M fp32
    const size_t csum_elems  = (size_t)BB * NCHUNK * PP; // 131K fp32
    const size_t w_elems     = (size_t)PP * KKDIM;       // 524K
    const size_t need2 = (delta_elems + csum_elems) * sizeof(float);
    const size_t need1 = need2 + 2 * w_elems * sizeof(unsigned short);  // ~19 MB

    if (ws_size >= need1) {
        float* delta = (float*)d_ws;
        float* csum  = delta + delta_elems;
        unsigned short* whi = (unsigned short*)(csum + csum_elems);
        unsigned short* wlo = whi + w_elems;
        cvt_k<<<w_elems / 1024, 256, 0, stream>>>(W, whi, wlo);
        gemm_n256_k<<<MM / 64, 256, 0, stream>>>(x, whi, wlo, bias, delta, csum);
        scan_lds_k<<<(BB * PP) / 2, 256, 0, stream>>>(csum);
        rotate_copy2_k<<<BB * NCHUNK, 256, 0, stream>>>(delta, csum, x, out);
    } else if (ws_size >= need2) {
        float* delta = (float*)d_ws;
        float* csum  = delta + delta_elems;
        gemm_mfma_k<<<dim3(PP / 64, MM / 128), 256, 0, stream>>>(x, W, bias, delta, csum);
        scan_k<<<(BB * PP) / 256, 256, 0, stream>>>(csum, PP);
        rotate_copy_k<<<BB * NCHUNK, 256, 0, stream>>>(delta, csum, x, out);
    } else {
        float* delta = out; const int dstride = DDIM, doff = 512;
        float* csum  = out + 768; const int cstride = DDIM;
        gemm_k<<<dim3(MM / 64, PP / 64), 256, 0, stream>>>(x, W, bias, delta, dstride, doff);
        chunksum_k<<<BB * NCHUNK, 256, 0, stream>>>(delta, dstride, doff, csum, cstride);
        scan_k<<<(BB * PP) / 256, 256, 0, stream>>>(csum, cstride);
        rotate_k<<<BB * NCHUNK, 256, 0, stream>>>(delta, dstride, doff, csum, cstride, x, out);
        copy_k<<<dim3(MM / 4, 6), 256, 0, stream>>>(x, out);
    }
}